// Round 7
// baseline (139.162 us; speedup 1.0000x reference)
//
#include <hip/hip_runtime.h>
#include <hip/hip_bf16.h>

// Gram reassociation, short-chain form (no softmax in reference):
//   O_h = X_h Wq^T Wk G Wv^T,  G = X_h^T X_h
//   M^T = gemm_bt(WkT, WqT)       (= Wk^T Wq)
//   G   = gemm_bt(xt_h, xt_h)     (split-K8)      [B1, one hetero launch w/ Mt]
//   Q'  = gemm_bt(xb_h, Mt_h)     (= X M)         [B2, batched w/ Zt]
//   Zt  = gemm_bt(Wv_h, G_h)      (= Wv G, split-K4)
//   O   = gemm_bt(Q'_h, Zt_h) = X M G Wv^T -> f32 out
// 6 launches (was 8): prep, B1, redGM, B2, redZ, O. Split-K partials (bf16)
// staged in d_out while it's dead. XCD-chunked swizzle everywhere (nwg%8==0).

using bf16 = __hip_bfloat16;
typedef __attribute__((ext_vector_type(8))) __bf16 bf16x8;
typedef __attribute__((ext_vector_type(8))) unsigned short u16x8;
typedef __attribute__((ext_vector_type(4))) float f32x4;

#define M1 (1024 * 1024)

struct GBH {   // heterogeneous per-z batch (wave-uniform scalar tables)
    const bf16* A[20];
    const bf16* B[20];
    void*       C[20];
    int lda[20], ldb[20], ldc[20];
    int gxl[20];        // log2(tiles in n-dim) — always pow2 here
    int ksub[20];
    int blk_off[21];    // prefix sum of blocks per z
    int nz;
};

__device__ __forceinline__ void gload_lds16(const void* g, void* l) {
    __builtin_amdgcn_global_load_lds(
        (const __attribute__((address_space(1))) void*)g,
        (__attribute__((address_space(3))) void*)l, 16, 0, 0);
}

__device__ __forceinline__ void storeC(bf16* C, size_t idx, float v) {
    C[idx] = __float2bfloat16(v);
}
__device__ __forceinline__ void storeC(float* C, size_t idx, float v) {
    C[idx] = v;
}

// A: rows x K (lda), B: cols x K (ldb); C = A B^T (ldc). 1-D grid = nwg blocks.
// 4 waves in 2x2 over (BM_/2)x(BN_/2) subtiles; m97 staging/MFMA structure.
template<int BM_, int BN_, typename OUT_T>
__global__ __launch_bounds__(256, 4)
void gemm_bt_h(GBH g, int nwg)
{
    // XCD-chunked swizzle (T1): contiguous chunk of wg per XCD
    const int orig = blockIdx.x;
    const int cpx = nwg >> 3;
    const int wg = (orig & 7) * cpx + (orig >> 3);

    int z = 0;
    while (z + 1 < g.nz && wg >= g.blk_off[z + 1]) ++z;
    const int local = wg - g.blk_off[z];
    const int gxl = g.gxl[z];
    const int bx = local & ((1 << gxl) - 1);
    const int by = local >> gxl;

    const bf16* __restrict__ A = g.A[z];
    const bf16* __restrict__ B = g.B[z];
    OUT_T* __restrict__ C = (OUT_T*)g.C[z];
    const int lda = g.lda[z];
    const int ldb = g.ldb[z];
    const int ldc = g.ldc[z];
    const int Ksub = g.ksub[z];

    __shared__ unsigned short As[BM_ * 32];   // linear (global_load_lds)
    __shared__ unsigned short Bs[BN_ * 32];

    constexpr int MI = BM_ / 32;
    constexpr int NI = BN_ / 32;

    const int tid  = threadIdx.x;
    const int lane = tid & 63;
    const int wave = tid >> 6;
    const int wm   = wave >> 1;
    const int wn   = wave & 1;

    const int m0 = by * BM_;
    const int n0 = bx * BN_;

    const int fr = lane & 15;
    const int kg = lane >> 4;

    const int srow = tid >> 2;
    const int scol = (tid & 3) * 8;

    f32x4 acc[MI][NI];
    #pragma unroll
    for (int i = 0; i < MI; ++i)
        #pragma unroll
        for (int j = 0; j < NI; ++j)
            acc[i][j] = {0.f, 0.f, 0.f, 0.f};

    for (int kt = 0; kt < Ksub; kt += 32) {
        #pragma unroll
        for (int r = 0; r < BM_ / 64; ++r) {
            const bf16* gA = A + (size_t)(m0 + r * 64 + srow) * lda + (kt + scol);
            gload_lds16(gA, &As[(r * 64 + srow) * 32 + scol]);
        }
        #pragma unroll
        for (int r = 0; r < BN_ / 64; ++r) {
            const bf16* gB = B + (size_t)(n0 + r * 64 + srow) * ldb + (kt + scol);
            gload_lds16(gB, &Bs[(r * 64 + srow) * 32 + scol]);
        }
        __syncthreads();

        bf16x8 afrag[MI], bfrag[NI];
        #pragma unroll
        for (int mi = 0; mi < MI; ++mi)
            afrag[mi] = *(const bf16x8*)&As[(wm * (BM_ / 2) + mi * 16 + fr) * 32 + kg * 8];
        #pragma unroll
        for (int ni = 0; ni < NI; ++ni)
            bfrag[ni] = *(const bf16x8*)&Bs[(wn * (BN_ / 2) + ni * 16 + fr) * 32 + kg * 8];

        #pragma unroll
        for (int mi = 0; mi < MI; ++mi)
            #pragma unroll
            for (int ni = 0; ni < NI; ++ni)
                acc[mi][ni] = __builtin_amdgcn_mfma_f32_16x16x32_bf16(
                    afrag[mi], bfrag[ni], acc[mi][ni], 0, 0, 0);
        __syncthreads();
    }

    // C/D layout: col = lane&15, row = (lane>>4)*4 + j  [m89-verified]
    #pragma unroll
    for (int mi = 0; mi < MI; ++mi) {
        #pragma unroll
        for (int ni = 0; ni < NI; ++ni) {
            const int col = n0 + wn * (BN_ / 2) + ni * 16 + fr;
            #pragma unroll
            for (int j = 0; j < 4; ++j) {
                const int row = m0 + wm * (BM_ / 2) + mi * 16 + kg * 4 + j;
                storeC(C, (size_t)row * ldc + col, acc[mi][ni][j]);
            }
        }
    }
}

// ---------------- prep: casts + transposes ----------------

__device__ __forceinline__ ushort4 cvt4(float4 v) {
    ushort4 o; bf16 h;
    h = __float2bfloat16(v.x); o.x = *(unsigned short*)&h;
    h = __float2bfloat16(v.y); o.y = *(unsigned short*)&h;
    h = __float2bfloat16(v.z); o.z = *(unsigned short*)&h;
    h = __float2bfloat16(v.w); o.w = *(unsigned short*)&h;
    return o;
}

struct PrepArgs {
    const float* x;
    const float* w[4];    // Wq1, Wq2, Wk1, Wk2 (to transpose)
    const float* wv[2];   // Wv1, Wv2 (straight)
    bf16* xb;             // 4096x2048 bf16
    bf16* xt;             // 2048x4096 bf16 (= x^T)
    bf16* wdst;           // WqT0,WqT1,WkT0,WkT1,Wv0,Wv1 (6 x 1M)
};

__device__ void xpose64(const float* __restrict__ src, int ldsrc,
                        int r0, int c0,
                        bf16* __restrict__ dstS, int ldS,
                        bf16* __restrict__ dstT, int ldT,
                        float (*tile)[65], int t)
{
    const int tr  = t >> 4;
    const int tc4 = (t & 15) * 4;
    #pragma unroll
    for (int ph = 0; ph < 4; ++ph) {
        const int row = ph * 16 + tr;
        float4 v = *(const float4*)(src + (size_t)(r0 + row) * ldsrc + c0 + tc4);
        tile[row][tc4 + 0] = v.x;
        tile[row][tc4 + 1] = v.y;
        tile[row][tc4 + 2] = v.z;
        tile[row][tc4 + 3] = v.w;
        if (dstS)
            *(ushort4*)((unsigned short*)dstS + (size_t)(r0 + row) * ldS + c0 + tc4) = cvt4(v);
    }
    __syncthreads();
    #pragma unroll
    for (int ph = 0; ph < 4; ++ph) {
        const int crow = ph * 16 + tr;
        float4 v = {tile[tc4 + 0][crow], tile[tc4 + 1][crow],
                    tile[tc4 + 2][crow], tile[tc4 + 3][crow]};
        *(ushort4*)((unsigned short*)dstT + (size_t)(c0 + crow) * ldT + r0 + tc4) = cvt4(v);
    }
}

__global__ void prep(PrepArgs p)
{
    __shared__ float tile[64][65];
    const int b = blockIdx.x;
    const int t = threadIdx.x;

    if (b < 2048) {                       // x: cast + transpose
        const int n0 = (b & 63) * 64;
        const int c0 = (b >> 6) * 64;
        xpose64(p.x, 2048, n0, c0, p.xb, 2048, p.xt, 4096, tile, t);
    } else if (b < 3072) {                // Wq/Wk transpose-cast
        const int i = b - 2048;
        const int mat = i >> 8;
        const int tl  = i & 255;
        const int r0 = (tl & 15) * 64;
        const int c0 = (tl >> 4) * 64;
        xpose64(p.w[mat], 1024, r0, c0, nullptr, 0,
                p.wdst + (size_t)mat * M1, 1024, tile, t);
    } else {                              // Wv straight cast
        const int i = b - 3072;
        const int mat = i >> 9;
        const int blk = i & 511;
        const size_t off = (size_t)blk * 2048 + t * 8;
        float4 v0 = *(const float4*)(p.wv[mat] + off);
        float4 v1 = *(const float4*)(p.wv[mat] + off + 4);
        unsigned short* d = (unsigned short*)p.wdst + (size_t)(4 + mat) * M1 + off;
        *(ushort4*)d       = cvt4(v0);
        *(ushort4*)(d + 4) = cvt4(v1);
    }
}

// ---------------- split-K reduces (bf16 partials, f32 accum) ----------------

__device__ __forceinline__ void reduce_slices(const unsigned short* src,
                                              unsigned short* dst,
                                              int h, int r, int nslice)
{
    float acc[8] = {0, 0, 0, 0, 0, 0, 0, 0};
    for (int s = 0; s < nslice; ++s) {
        u16x8 v = *(const u16x8*)(src + ((size_t)(h * nslice + s) << 20) + r);
        #pragma unroll
        for (int j = 0; j < 8; ++j)
            acc[j] += __uint_as_float(((unsigned)v[j]) << 16);
    }
    u16x8 o;
    #pragma unroll
    for (int j = 0; j < 8; ++j) {
        bf16 hh = __float2bfloat16(acc[j]);
        o[j] = *(unsigned short*)&hh;
    }
    *(u16x8*)(dst + ((size_t)h << 20) + r) = o;
}

// blocks 0..1023: G (8 slices, from d_out scratch); 1024..2047: Mt (2 slices)
__global__ void reduce_GM(const unsigned short* Gp, const unsigned short* Mp,
                          unsigned short* Gd, unsigned short* Md)
{
    const int b = blockIdx.x, t = threadIdx.x;
    if (b < 1024) {
        const int e = (b * 256 + t) * 8;
        reduce_slices(Gp, Gd, e >> 20, e & (M1 - 1), 8);
    } else {
        const int e = ((b - 1024) * 256 + t) * 8;
        reduce_slices(Mp, Md, e >> 20, e & (M1 - 1), 2);
    }
}

__global__ void reduce_4(const unsigned short* Sp, unsigned short* Dd)
{
    const int e = (blockIdx.x * 256 + threadIdx.x) * 8;
    reduce_slices(Sp, Dd, e >> 20, e & (M1 - 1), 4);
}

// ---------------- driver ----------------

extern "C" void kernel_launch(void* const* d_in, const int* in_sizes, int n_in,
                              void* d_out, int out_size, void* d_ws, size_t ws_size,
                              hipStream_t stream)
{
    // ws layout (bf16 elems): 80 MB peak (<=84 proven)
    bf16* xb   = (bf16*)d_ws;                  // 8M elems (16 MB)
    bf16* xt   = xb + 8 * M1;                  // 8M
    bf16* wdst = xt + 8 * M1;                  // 6M: WqT0,WqT1,WkT0,WkT1,Wv0,Wv1
    bf16* Mp   = wdst + 6 * M1;                // 4M  (Mt split-K2 partials)
    bf16* Mtb  = Mp + 4 * M1;                  // 2M  (Mt = Wk^T Wq, both heads)
    bf16* Gb   = Mtb + 2 * M1;                 // 2M
    bf16* Qp   = Gb + 2 * M1;                  // 8M  (Q' = X M, both heads)
    bf16* Ztb  = Qp + 8 * M1;                  // 2M  (Zt = Wv G)

    bf16* scr = (bf16*)d_out;                  // 32 MB scratch until final O

    PrepArgs pa;
    pa.x = (const float*)d_in[0];
    pa.w[0] = (const float*)d_in[1];  pa.w[1] = (const float*)d_in[2];
    pa.w[2] = (const float*)d_in[3];  pa.w[3] = (const float*)d_in[4];
    pa.wv[0] = (const float*)d_in[5]; pa.wv[1] = (const float*)d_in[6];
    pa.xb = xb; pa.xt = xt; pa.wdst = wdst;
    prep<<<4096, 256, 0, stream>>>(pa);

    GBH g;

    // B1: z 0..15: G_h split-K8 (Ksub=512, 64 blk each);
    //     z 16..19: Mt_h = gemm_bt(WkT, WqT) split-K2 (Ksub=512, 64 blk each)
    for (int z = 0; z < 16; ++z) {
        const int h = z >> 3, s = z & 7;
        g.A[z] = xt + (size_t)h * 4 * M1 + s * 512;  g.lda[z] = 4096;
        g.B[z] = g.A[z];                             g.ldb[z] = 4096;
        g.C[z] = (bf16*)scr + (size_t)z * M1;        g.ldc[z] = 1024;
        g.gxl[z] = 3; g.ksub[z] = 512; g.blk_off[z] = z * 64;
    }
    for (int z = 16; z < 20; ++z) {
        const int j = z - 16, h = j >> 1, s = j & 1;
        g.A[z] = wdst + (size_t)(2 + h) * M1 + s * 512;  g.lda[z] = 1024;  // WkT_h
        g.B[z] = wdst + (size_t)h * M1 + s * 512;        g.ldb[z] = 1024;  // WqT_h
        g.C[z] = Mp + (size_t)j * M1;                    g.ldc[z] = 1024;
        g.gxl[z] = 3; g.ksub[z] = 512; g.blk_off[z] = z * 64;
    }
    g.blk_off[20] = 1280; g.nz = 20;
    gemm_bt_h<128, 128, bf16><<<1280, 256, 0, stream>>>(g, 1280);

    reduce_GM<<<2048, 256, 0, stream>>>((const unsigned short*)scr, (const unsigned short*)Mp,
                                        (unsigned short*)Gb, (unsigned short*)Mtb);

    // B2: z 0..1: Q'_h = gemm_bt(xb_h, Mt_h), 8x32 tiles = 256 blk, Ksub=1024;
    //     z 2..9: Zt_h = gemm_bt(Wv_h, G_h) split-K4 (Ksub=256, 64 blk each)
    for (int h = 0; h < 2; ++h) {
        g.A[h] = xb + (size_t)h * 1024;        g.lda[h] = 2048;
        g.B[h] = Mtb + (size_t)h * M1;         g.ldb[h] = 1024;
        g.C[h] = Qp + (size_t)h * 4 * M1;      g.ldc[h] = 1024;
        g.gxl[h] = 3; g.ksub[h] = 1024; g.blk_off[h] = h * 256;
    }
    for (int z = 2; z < 10; ++z) {
        const int j = z - 2, h = j >> 2, s = j & 3;
        g.A[z] = wdst + (size_t)(4 + h) * M1 + s * 256;  g.lda[z] = 1024;  // Wv_h
        g.B[z] = Gb + (size_t)h * M1 + s * 256;          g.ldb[z] = 1024;
        g.C[z] = (bf16*)scr + (size_t)j * M1;            g.ldc[z] = 1024;
        g.gxl[z] = 3; g.ksub[z] = 256; g.blk_off[z] = 512 + j * 64;
    }
    g.blk_off[10] = 1024; g.nz = 10;
    gemm_bt_h<128, 128, bf16><<<1024, 256, 0, stream>>>(g, 1024);

    reduce_4<<<1024, 256, 0, stream>>>((const unsigned short*)scr, (unsigned short*)Ztb);

    // O: z 0..1: O_h = gemm_bt(Q'_h, Zt_h) -> f32 out[:, h*1024:], 128x64 tile,
    //    16x32 tiles = 512 blk each, Ksub=1024
    for (int h = 0; h < 2; ++h) {
        g.A[h] = Qp + (size_t)h * 4 * M1;      g.lda[h] = 1024;
        g.B[h] = Ztb + (size_t)h * M1;         g.ldb[h] = 1024;
        g.C[h] = (float*)d_out + (size_t)h * 1024;  g.ldc[h] = 2048;
        g.gxl[h] = 4; g.ksub[h] = 1024; g.blk_off[h] = h * 512;
    }
    g.blk_off[2] = 1024; g.nz = 2;
    gemm_bt_h<128, 64, float><<<1024, 256, 0, stream>>>(g, 1024);
}

// Round 9
// 128.265 us; speedup vs baseline: 1.0850x; 1.0850x over previous
//
#include <hip/hip_runtime.h>
#include <hip/hip_bf16.h>

// Gram reassociation (no softmax in reference):
//   O_h = Q K^T V = X_h * U_h,  U_h = Wq^T Wk G Wv^T,  G = X_h^T X_h
// R6 DAG (proven 126.7us): prep -> B1{G splitK8 || Mt splitK2} -> redGM ->
//   Yt=M G (splitK4) -> red4 -> Ut=Wv Yt (splitK4) -> red4 -> O=X Ut^T.
// R8 change: double-buffered LDS + counted-vmcnt 2-phase K-loop (T3min+T4):
//   stage(t+1) issued BEFORE compute(t); s_waitcnt vmcnt(4) (not 0) so the
//   fresh stage stays in flight across the barrier. Attacks the measured
//   ~1800cy/iter stage->drain->compute serialization (MfmaUtil 16%, FETCH
//   already minimal after XCD swizzle).

using bf16 = __hip_bfloat16;
typedef __attribute__((ext_vector_type(8))) __bf16 bf16x8;
typedef __attribute__((ext_vector_type(8))) unsigned short u16x8;
typedef __attribute__((ext_vector_type(4))) float f32x4;

#define M1 (1024 * 1024)

struct GB {   // per-z batch (blockIdx.z-indexed, wave-uniform)
    const bf16* A[20];
    const bf16* B[20];
    void*       C[20];
    int lda[20];
    int ldb[20];
};

__device__ __forceinline__ void gload_lds16(const void* g, void* l) {
    __builtin_amdgcn_global_load_lds(
        (const __attribute__((address_space(1))) void*)g,
        (__attribute__((address_space(3))) void*)l, 16, 0, 0);
}

template<int N>
__device__ __forceinline__ void waitv() {
    if constexpr (N == 4)      asm volatile("s_waitcnt vmcnt(4)" ::: "memory");
    else if constexpr (N == 3) asm volatile("s_waitcnt vmcnt(3)" ::: "memory");
    else                       asm volatile("s_waitcnt vmcnt(0)" ::: "memory");
}

__device__ __forceinline__ void storeC(bf16* C, size_t idx, float v) {
    C[idx] = __float2bfloat16(v);
}
__device__ __forceinline__ void storeC(float* C, size_t idx, float v) {
    C[idx] = v;
}

// A: rows x K (lda), B: cols x K (ldb); C = A B^T (ldc).
// grid: (n-tiles, m-tiles, z). 4 waves 2x2 over (BM_/2)x(BN_/2) subtiles.
// XCD-chunked swizzle on linearized id (nwg % 8 == 0 for all launches).
template<int BM_, int BN_, typename OUT_T>
__global__ __launch_bounds__(256, 4)
void gemm_bt_pa(GB g, int Ksub, int ldc)
{
    const int gx = gridDim.x, gy = gridDim.y;
    const int nwg = gx * gy * gridDim.z;
    const int orig = blockIdx.x + gx * (blockIdx.y + gy * blockIdx.z);
    const int cpx = nwg >> 3;
    const int wg = (orig & 7) * cpx + (orig >> 3);
    const int bx = wg % gx;
    const int by = (wg / gx) % gy;
    const int bz = wg / (gx * gy);

    const bf16* __restrict__ A = g.A[bz];
    const bf16* __restrict__ B = g.B[bz];
    OUT_T* __restrict__ C = (OUT_T*)g.C[bz];
    const int lda = g.lda[bz];
    const int ldb = g.ldb[bz];

    __shared__ unsigned short As[2][BM_ * 32];   // linear (global_load_lds dest)
    __shared__ unsigned short Bs[2][BN_ * 32];

    constexpr int MI = BM_ / 32;
    constexpr int NI = BN_ / 32;
    constexpr int NLOADS = (BM_ + BN_) / 64;     // gload_lds per thread per stage

    const int tid  = threadIdx.x;
    const int lane = tid & 63;
    const int wave = tid >> 6;
    const int wm   = wave >> 1;
    const int wn   = wave & 1;

    const int m0 = by * BM_;
    const int n0 = bx * BN_;

    const int fr = lane & 15;
    const int kg = lane >> 4;

    const int srow = tid >> 2;
    const int scol = (tid & 3) * 8;

    auto stage = [&](int buf, int kt) {
        #pragma unroll
        for (int r = 0; r < BM_ / 64; ++r)
            gload_lds16(A + (size_t)(m0 + r * 64 + srow) * lda + (kt + scol),
                        &As[buf][(r * 64 + srow) * 32 + scol]);
        #pragma unroll
        for (int r = 0; r < BN_ / 64; ++r)
            gload_lds16(B + (size_t)(n0 + r * 64 + srow) * ldb + (kt + scol),
                        &Bs[buf][(r * 64 + srow) * 32 + scol]);
    };

    f32x4 acc[MI][NI];
    #pragma unroll
    for (int i = 0; i < MI; ++i)
        #pragma unroll
        for (int j = 0; j < NI; ++j)
            acc[i][j] = {0.f, 0.f, 0.f, 0.f};

    const int niter = Ksub >> 5;
    int cur = 0;
    stage(0, 0);                                  // prologue: tile 0 in flight

    for (int it = 0; it < niter; ++it) {
        if (it + 1 < niter) {
            stage(cur ^ 1, (it + 1) << 5);        // issue next tile FIRST
            waitv<NLOADS>();                      // oldest stage (cur) done
        } else {
            waitv<0>();
        }
        __builtin_amdgcn_s_barrier();             // all waves: buf[cur] filled
        __builtin_amdgcn_sched_barrier(0);

        bf16x8 afrag[MI], bfrag[NI];
        #pragma unroll
        for (int mi = 0; mi < MI; ++mi)
            afrag[mi] = *(const bf16x8*)&As[cur][(wm * (BM_ / 2) + mi * 16 + fr) * 32 + kg * 8];
        #pragma unroll
        for (int ni = 0; ni < NI; ++ni)
            bfrag[ni] = *(const bf16x8*)&Bs[cur][(wn * (BN_ / 2) + ni * 16 + fr) * 32 + kg * 8];

        #pragma unroll
        for (int mi = 0; mi < MI; ++mi)
            #pragma unroll
            for (int ni = 0; ni < NI; ++ni)
                acc[mi][ni] = __builtin_amdgcn_mfma_f32_16x16x32_bf16(
                    afrag[mi], bfrag[ni], acc[mi][ni], 0, 0, 0);

        __builtin_amdgcn_sched_barrier(0);
        __builtin_amdgcn_s_barrier();             // reads of buf[cur] done
        __builtin_amdgcn_sched_barrier(0);        // before next overwrite
        cur ^= 1;
    }

    // C/D layout: col = lane&15, row = (lane>>4)*4 + j  [m89-verified]
    #pragma unroll
    for (int mi = 0; mi < MI; ++mi) {
        #pragma unroll
        for (int ni = 0; ni < NI; ++ni) {
            const int col = n0 + wn * (BN_ / 2) + ni * 16 + fr;
            #pragma unroll
            for (int j = 0; j < 4; ++j) {
                const int row = m0 + wm * (BM_ / 2) + mi * 16 + kg * 4 + j;
                storeC(C, (size_t)row * ldc + col, acc[mi][ni][j]);
            }
        }
    }
}

// ---------------- prep: casts + transposes ----------------

__device__ __forceinline__ ushort4 cvt4(float4 v) {
    ushort4 o; bf16 h;
    h = __float2bfloat16(v.x); o.x = *(unsigned short*)&h;
    h = __float2bfloat16(v.y); o.y = *(unsigned short*)&h;
    h = __float2bfloat16(v.z); o.z = *(unsigned short*)&h;
    h = __float2bfloat16(v.w); o.w = *(unsigned short*)&h;
    return o;
}

struct PrepArgs {
    const float* x;
    const float* w[4];    // Wq1, Wq2, Wk1, Wk2 (to transpose)
    const float* wv[2];   // Wv1, Wv2 (straight)
    bf16* xb;             // 4096x2048 bf16
    bf16* xt;             // 2048x4096 bf16 (= x^T)
    bf16* wdst;           // WqT0,WqT1,WkT0,WkT1,Wv0,Wv1 (6 x 1M)
};

__device__ void xpose64(const float* __restrict__ src, int ldsrc,
                        int r0, int c0,
                        bf16* __restrict__ dstS, int ldS,
                        bf16* __restrict__ dstT, int ldT,
                        float (*tile)[65], int t)
{
    const int tr  = t >> 4;
    const int tc4 = (t & 15) * 4;
    #pragma unroll
    for (int ph = 0; ph < 4; ++ph) {
        const int row = ph * 16 + tr;
        float4 v = *(const float4*)(src + (size_t)(r0 + row) * ldsrc + c0 + tc4);
        tile[row][tc4 + 0] = v.x;
        tile[row][tc4 + 1] = v.y;
        tile[row][tc4 + 2] = v.z;
        tile[row][tc4 + 3] = v.w;
        if (dstS)
            *(ushort4*)((unsigned short*)dstS + (size_t)(r0 + row) * ldS + c0 + tc4) = cvt4(v);
    }
    __syncthreads();
    #pragma unroll
    for (int ph = 0; ph < 4; ++ph) {
        const int crow = ph * 16 + tr;
        float4 v = {tile[tc4 + 0][crow], tile[tc4 + 1][crow],
                    tile[tc4 + 2][crow], tile[tc4 + 3][crow]};
        *(ushort4*)((unsigned short*)dstT + (size_t)(c0 + crow) * ldT + r0 + tc4) = cvt4(v);
    }
}

__global__ void prep(PrepArgs p)
{
    __shared__ float tile[64][65];
    const int b = blockIdx.x;
    const int t = threadIdx.x;

    if (b < 2048) {                       // x: cast + transpose
        const int n0 = (b & 63) * 64;
        const int c0 = (b >> 6) * 64;
        xpose64(p.x, 2048, n0, c0, p.xb, 2048, p.xt, 4096, tile, t);
    } else if (b < 3072) {                // Wq/Wk transpose-cast
        const int i = b - 2048;
        const int mat = i >> 8;
        const int tl  = i & 255;
        const int r0 = (tl & 15) * 64;
        const int c0 = (tl >> 4) * 64;
        xpose64(p.w[mat], 1024, r0, c0, nullptr, 0,
                p.wdst + (size_t)mat * M1, 1024, tile, t);
    } else {                              // Wv straight cast
        const int i = b - 3072;
        const int mat = i >> 9;
        const int blk = i & 511;
        const size_t off = (size_t)blk * 2048 + t * 8;
        float4 v0 = *(const float4*)(p.wv[mat] + off);
        float4 v1 = *(const float4*)(p.wv[mat] + off + 4);
        unsigned short* d = (unsigned short*)p.wdst + (size_t)(4 + mat) * M1 + off;
        *(ushort4*)d       = cvt4(v0);
        *(ushort4*)(d + 4) = cvt4(v1);
    }
}

// ---------------- split-K reduces (bf16 partials, f32 accum) ----------------

__device__ __forceinline__ void reduce_slices(const unsigned short* src,
                                              unsigned short* dst,
                                              int h, int r, int nslice)
{
    float acc[8] = {0, 0, 0, 0, 0, 0, 0, 0};
    for (int s = 0; s < nslice; ++s) {
        u16x8 v = *(const u16x8*)(src + ((size_t)(h * nslice + s) << 20) + r);
        #pragma unroll
        for (int j = 0; j < 8; ++j)
            acc[j] += __uint_as_float(((unsigned)v[j]) << 16);
    }
    u16x8 o;
    #pragma unroll
    for (int j = 0; j < 8; ++j) {
        bf16 hh = __float2bfloat16(acc[j]);
        o[j] = *(unsigned short*)&hh;
    }
    *(u16x8*)(dst + ((size_t)h << 20) + r) = o;
}

__global__ void reduce_GM(const unsigned short* Gp, const unsigned short* Mp,
                          unsigned short* Gd, unsigned short* Md)
{
    const int b = blockIdx.x, t = threadIdx.x;
    if (b < 1024) {
        const int e = (b * 256 + t) * 8;
        reduce_slices(Gp, Gd, e >> 20, e & (M1 - 1), 8);
    } else {
        const int e = ((b - 1024) * 256 + t) * 8;
        reduce_slices(Mp, Md, e >> 20, e & (M1 - 1), 2);
    }
}

__global__ void reduce_4(const unsigned short* Sp, unsigned short* Dd)
{
    const int e = (blockIdx.x * 256 + threadIdx.x) * 8;
    reduce_slices(Sp, Dd, e >> 20, e & (M1 - 1), 4);
}

// ---------------- driver (R6 schedule, unchanged) ----------------

extern "C" void kernel_launch(void* const* d_in, const int* in_sizes, int n_in,
                              void* d_out, int out_size, void* d_ws, size_t ws_size,
                              hipStream_t stream)
{
    // ws layout (bf16 elems): peak 68 MB
    bf16* xb   = (bf16*)d_ws;                  // 8M elems
    bf16* xt   = xb + 8 * M1;                  // 8M
    bf16* wdst = xt + 8 * M1;                  // 6M
    bf16* Mp   = wdst + 6 * M1;                // 4M
    bf16* Mb   = Mp + 4 * M1;                  // 2M
    bf16* Gb   = Mb + 2 * M1;                  // 2M
    bf16* Ytb  = Gb + 2 * M1;                  // 2M
    bf16* Utb  = Ytb + 2 * M1;                 // 2M

    bf16* scr = (bf16*)d_out;                  // 32 MB scratch until final O

    PrepArgs pa;
    pa.x = (const float*)d_in[0];
    pa.w[0] = (const float*)d_in[1];  pa.w[1] = (const float*)d_in[2];
    pa.w[2] = (const float*)d_in[3];  pa.w[3] = (const float*)d_in[4];
    pa.wv[0] = (const float*)d_in[5]; pa.wv[1] = (const float*)d_in[6];
    pa.xb = xb; pa.xt = xt; pa.wdst = wdst;
    prep<<<4096, 256, 0, stream>>>(pa);

    GB g;

    // B1: z 0..15: G_h split-K8 (Ksub=512); z 16..19: M_h split-K2. 1280 blocks.
    for (int z = 0; z < 16; ++z) {
        const int h = z >> 3, s = z & 7;
        g.A[z] = xt + (size_t)h * 4 * M1 + s * 512;  g.lda[z] = 4096;
        g.B[z] = g.A[z];                             g.ldb[z] = 4096;
        g.C[z] = (bf16*)scr + (size_t)z * M1;
    }
    for (int z = 16; z < 20; ++z) {
        const int j = z - 16, h = j >> 1, s = j & 1;
        g.A[z] = wdst + (size_t)h * M1 + s * 512;           g.lda[z] = 1024;
        g.B[z] = wdst + (size_t)(2 + h) * M1 + s * 512;     g.ldb[z] = 1024;
        g.C[z] = Mp + (size_t)j * M1;
    }
    gemm_bt_pa<128, 128, bf16><<<dim3(8, 8, 20), 256, 0, stream>>>(g, 512, 1024);

    reduce_GM<<<2048, 256, 0, stream>>>((const unsigned short*)scr, (const unsigned short*)Mp,
                                        (unsigned short*)Gb, (unsigned short*)Mb);

    // L4: Yt = M G (split-K4, Ksub=256), 512 blocks
    for (int z = 0; z < 8; ++z) {
        const int h = z >> 2, s = z & 3;
        g.A[z] = Mb + (size_t)h * M1 + s * 256;  g.lda[z] = 1024;
        g.B[z] = Gb + (size_t)h * M1 + s * 256;  g.ldb[z] = 1024;
        g.C[z] = (bf16*)scr + (size_t)z * M1;
    }
    gemm_bt_pa<128, 128, bf16><<<dim3(8, 8, 8), 256, 0, stream>>>(g, 256, 1024);

    reduce_4<<<1024, 256, 0, stream>>>((const unsigned short*)scr, (unsigned short*)Ytb);

    // L6: Ut = gemm_bt(Wv, Yt) (split-K4), 512 blocks
    for (int z = 0; z < 8; ++z) {
        const int h = z >> 2, s = z & 3;
        g.A[z] = wdst + (size_t)(4 + h) * M1 + s * 256;  g.lda[z] = 1024;
        g.B[z] = Ytb + (size_t)h * M1 + s * 256;         g.ldb[z] = 1024;
        g.C[z] = (bf16*)scr + (size_t)z * M1;
    }
    gemm_bt_pa<128, 128, bf16><<<dim3(8, 8, 8), 256, 0, stream>>>(g, 256, 1024);

    reduce_4<<<1024, 256, 0, stream>>>((const unsigned short*)scr, (unsigned short*)Utb);

    // L8: O_h = gemm_bt(X_h, Ut_h) -> f32 out[:, h*1024:]  (128x64 tile, 1024 blocks)
    for (int z = 0; z < 2; ++z) {
        g.A[z] = xb + (size_t)z * 1024;   g.lda[z] = 2048;
        g.B[z] = Utb + (size_t)z * M1;    g.ldb[z] = 1024;
        g.C[z] = (float*)d_out + (size_t)z * 1024;
    }
    gemm_bt_pa<128, 64, float><<<dim3(16, 32, 2), 256, 0, stream>>>(g, 1024, 2048);
}

// Round 11
// 124.300 us; speedup vs baseline: 1.1196x; 1.0319x over previous
//
#include <hip/hip_runtime.h>
#include <hip/hip_bf16.h>

// Gram reassociation (no softmax in reference):
//   O_h = Q K^T V = X_h * U_h,  U_h = Wq^T Wk G Wv^T,  G = X_h^T X_h
// DAG (R6-proven): prep -> B1{G splitK8 || Mt splitK2} -> redGM ->
//   Yt=M G (splitK4) -> red4 -> Ut=Wv Yt (splitK4) -> red4 -> O=X Ut^T.
// R11 = R9's K-loop (dbuf + counted vmcnt + FULL sched_barrier fencing —
// proven deterministic) + R10's LDS-staged coalesced epilogue (which raced
// in R10 only because the sched_barrier fences were dropped; rule #18:
// s_barrier is not a compiler memory fence).

using bf16 = __hip_bfloat16;
typedef __attribute__((ext_vector_type(8))) __bf16 bf16x8;
typedef __attribute__((ext_vector_type(8))) unsigned short u16x8;
typedef __attribute__((ext_vector_type(4))) float f32x4;

#define M1 (1024 * 1024)

struct GB {   // per-z batch (blockIdx.z-indexed, wave-uniform)
    const bf16* A[20];
    const bf16* B[20];
    void*       C[20];
    int lda[20];
    int ldb[20];
};

__device__ __forceinline__ void gload_lds16(const void* g, void* l) {
    __builtin_amdgcn_global_load_lds(
        (const __attribute__((address_space(1))) void*)g,
        (__attribute__((address_space(3))) void*)l, 16, 0, 0);
}

template<int N>
__device__ __forceinline__ void waitv() {
    if constexpr (N == 4)      asm volatile("s_waitcnt vmcnt(4)" ::: "memory");
    else if constexpr (N == 3) asm volatile("s_waitcnt vmcnt(3)" ::: "memory");
    else                       asm volatile("s_waitcnt vmcnt(0)" ::: "memory");
}

// A: rows x K (lda), B: cols x K (ldb); C = A B^T (ldc).
// grid: (n-tiles, m-tiles, z). 4 waves 2x2 over (BM_/2)x(BN_/2) subtiles.
// XCD-chunked swizzle on linearized id (nwg % 8 == 0 for all launches).
template<int BM_, int BN_, typename OUT_T>
__global__ __launch_bounds__(256, 4)
void gemm_bt_pa(GB g, int Ksub, int ldc)
{
    const int gx = gridDim.x, gy = gridDim.y;
    const int nwg = gx * gy * gridDim.z;
    const int orig = blockIdx.x + gx * (blockIdx.y + gy * blockIdx.z);
    const int cpx = nwg >> 3;
    const int wg = (orig & 7) * cpx + (orig >> 3);
    const int bx = wg % gx;
    const int by = (wg / gx) % gy;
    const int bz = wg / (gx * gy);

    const bf16* __restrict__ A = g.A[bz];
    const bf16* __restrict__ B = g.B[bz];
    OUT_T* __restrict__ C = (OUT_T*)g.C[bz];
    const int lda = g.lda[bz];
    const int ldb = g.ldb[bz];

    // one LDS pool: dbuf staging during K-loop; output tile in epilogue
    constexpr int STAGE_SH = 2 * (BM_ + BN_) * 32;                 // shorts
    constexpr int EPI_SH   = BM_ * BN_ * (int)sizeof(OUT_T) / 2;   // shorts
    constexpr int SMEM_SH  = STAGE_SH > EPI_SH ? STAGE_SH : EPI_SH;
    __shared__ __align__(16) unsigned short smem[SMEM_SH];
    auto As = (unsigned short(*)[BM_ * 32])smem;                   // [2][BM_*32]
    auto Bs = (unsigned short(*)[BN_ * 32])(smem + 2 * BM_ * 32);  // [2][BN_*32]

    constexpr int MI = BM_ / 32;
    constexpr int NI = BN_ / 32;
    constexpr int NLOADS = (BM_ + BN_) / 64;     // gload_lds per thread per stage

    const int tid  = threadIdx.x;
    const int lane = tid & 63;
    const int wave = tid >> 6;
    const int wm   = wave >> 1;
    const int wn   = wave & 1;

    const int m0 = by * BM_;
    const int n0 = bx * BN_;

    const int fr = lane & 15;
    const int kg = lane >> 4;

    const int srow = tid >> 2;
    const int scol = (tid & 3) * 8;

    auto stage = [&](int buf, int kt) {
        #pragma unroll
        for (int r = 0; r < BM_ / 64; ++r)
            gload_lds16(A + (size_t)(m0 + r * 64 + srow) * lda + (kt + scol),
                        &As[buf][(r * 64 + srow) * 32 + scol]);
        #pragma unroll
        for (int r = 0; r < BN_ / 64; ++r)
            gload_lds16(B + (size_t)(n0 + r * 64 + srow) * ldb + (kt + scol),
                        &Bs[buf][(r * 64 + srow) * 32 + scol]);
    };

    f32x4 acc[MI][NI];
    #pragma unroll
    for (int i = 0; i < MI; ++i)
        #pragma unroll
        for (int j = 0; j < NI; ++j)
            acc[i][j] = {0.f, 0.f, 0.f, 0.f};

    const int niter = Ksub >> 5;
    int cur = 0;
    stage(0, 0);                                  // prologue: tile 0 in flight

    for (int it = 0; it < niter; ++it) {
        if (it + 1 < niter) {
            stage(cur ^ 1, (it + 1) << 5);        // issue next tile FIRST
            waitv<NLOADS>();                      // oldest stage (cur) done
        } else {
            waitv<0>();
        }
        __builtin_amdgcn_s_barrier();             // all waves: buf[cur] filled
        __builtin_amdgcn_sched_barrier(0);

        bf16x8 afrag[MI], bfrag[NI];
        #pragma unroll
        for (int mi = 0; mi < MI; ++mi)
            afrag[mi] = *(const bf16x8*)&As[cur][(wm * (BM_ / 2) + mi * 16 + fr) * 32 + kg * 8];
        #pragma unroll
        for (int ni = 0; ni < NI; ++ni)
            bfrag[ni] = *(const bf16x8*)&Bs[cur][(wn * (BN_ / 2) + ni * 16 + fr) * 32 + kg * 8];

        #pragma unroll
        for (int mi = 0; mi < MI; ++mi)
            #pragma unroll
            for (int ni = 0; ni < NI; ++ni)
                acc[mi][ni] = __builtin_amdgcn_mfma_f32_16x16x32_bf16(
                    afrag[mi], bfrag[ni], acc[mi][ni], 0, 0, 0);

        __builtin_amdgcn_sched_barrier(0);        // pin: MFMA/LDS-reads done
        __builtin_amdgcn_s_barrier();             // before anyone re-stages
        __builtin_amdgcn_sched_barrier(0);        // pin: nothing hoists above
        cur ^= 1;
    }

    // ---- epilogue: acc -> LDS tile -> coalesced streaming stores ----
    // safe: final loop barrier (+sched fence) => all staging reads complete.
    // C/D layout: col = lane&15, row = (lane>>4)*4 + j  [m89-verified]
    if constexpr (sizeof(OUT_T) == 2) {
        #pragma unroll
        for (int mi = 0; mi < MI; ++mi)
            #pragma unroll
            for (int ni = 0; ni < NI; ++ni) {
                const int c = wn * (BN_ / 2) + ni * 16 + fr;
                #pragma unroll
                for (int j = 0; j < 4; ++j) {
                    const int r = wm * (BM_ / 2) + mi * 16 + kg * 4 + j;
                    bf16 h = __float2bfloat16(acc[mi][ni][j]);
                    smem[r * BN_ + c] = *(unsigned short*)&h;
                }
            }
        __syncthreads();
        // off = v*2048 + tid*8: conflict-free LDS reads, 16-lane x 256B rows
        constexpr int V = (BM_ * BN_) / 2048;
        #pragma unroll
        for (int v = 0; v < V; ++v) {
            const int off = v * 2048 + tid * 8;
            const int r = off / BN_;
            const int c = off % BN_;
            *(u16x8*)((unsigned short*)C + (size_t)(m0 + r) * ldc + n0 + c) =
                *(const u16x8*)&smem[off];
        }
    } else {
        float* fs = (float*)smem;
        #pragma unroll
        for (int mi = 0; mi < MI; ++mi)
            #pragma unroll
            for (int ni = 0; ni < NI; ++ni) {
                const int c = wn * (BN_ / 2) + ni * 16 + fr;
                #pragma unroll
                for (int j = 0; j < 4; ++j) {
                    const int r = wm * (BM_ / 2) + mi * 16 + kg * 4 + j;
                    fs[r * BN_ + c] = acc[mi][ni][j];
                }
            }
        __syncthreads();
        constexpr int V = (BM_ * BN_) / 1024;
        #pragma unroll
        for (int v = 0; v < V; ++v) {
            const int off = v * 1024 + tid * 4;
            const int r = off / BN_;
            const int c = off % BN_;
            *(float4*)((float*)C + (size_t)(m0 + r) * ldc + n0 + c) =
                *(const float4*)&fs[off];
        }
    }
}

// ---------------- prep: casts + transposes ----------------

__device__ __forceinline__ ushort4 cvt4(float4 v) {
    ushort4 o; bf16 h;
    h = __float2bfloat16(v.x); o.x = *(unsigned short*)&h;
    h = __float2bfloat16(v.y); o.y = *(unsigned short*)&h;
    h = __float2bfloat16(v.z); o.z = *(unsigned short*)&h;
    h = __float2bfloat16(v.w); o.w = *(unsigned short*)&h;
    return o;
}

struct PrepArgs {
    const float* x;
    const float* w[4];    // Wq1, Wq2, Wk1, Wk2 (to transpose)
    const float* wv[2];   // Wv1, Wv2 (straight)
    bf16* xb;             // 4096x2048 bf16
    bf16* xt;             // 2048x4096 bf16 (= x^T)
    bf16* wdst;           // WqT0,WqT1,WkT0,WkT1,Wv0,Wv1 (6 x 1M)
};

__device__ void xpose64(const float* __restrict__ src, int ldsrc,
                        int r0, int c0,
                        bf16* __restrict__ dstS, int ldS,
                        bf16* __restrict__ dstT, int ldT,
                        float (*tile)[65], int t)
{
    const int tr  = t >> 4;
    const int tc4 = (t & 15) * 4;
    #pragma unroll
    for (int ph = 0; ph < 4; ++ph) {
        const int row = ph * 16 + tr;
        float4 v = *(const float4*)(src + (size_t)(r0 + row) * ldsrc + c0 + tc4);
        tile[row][tc4 + 0] = v.x;
        tile[row][tc4 + 1] = v.y;
        tile[row][tc4 + 2] = v.z;
        tile[row][tc4 + 3] = v.w;
        if (dstS)
            *(ushort4*)((unsigned short*)dstS + (size_t)(r0 + row) * ldS + c0 + tc4) = cvt4(v);
    }
    __syncthreads();
    #pragma unroll
    for (int ph = 0; ph < 4; ++ph) {
        const int crow = ph * 16 + tr;
        float4 v = {tile[tc4 + 0][crow], tile[tc4 + 1][crow],
                    tile[tc4 + 2][crow], tile[tc4 + 3][crow]};
        *(ushort4*)((unsigned short*)dstT + (size_t)(c0 + crow) * ldT + r0 + tc4) = cvt4(v);
    }
}

__global__ void prep(PrepArgs p)
{
    __shared__ float tile[64][65];
    const int b = blockIdx.x;
    const int t = threadIdx.x;

    if (b < 2048) {                       // x: cast + transpose
        const int n0 = (b & 63) * 64;
        const int c0 = (b >> 6) * 64;
        xpose64(p.x, 2048, n0, c0, p.xb, 2048, p.xt, 4096, tile, t);
    } else if (b < 3072) {                // Wq/Wk transpose-cast
        const int i = b - 2048;
        const int mat = i >> 8;
        const int tl  = i & 255;
        const int r0 = (tl & 15) * 64;
        const int c0 = (tl >> 4) * 64;
        xpose64(p.w[mat], 1024, r0, c0, nullptr, 0,
                p.wdst + (size_t)mat * M1, 1024, tile, t);
    } else {                              // Wv straight cast
        const int i = b - 3072;
        const int mat = i >> 9;
        const int blk = i & 511;
        const size_t off = (size_t)blk * 2048 + t * 8;
        float4 v0 = *(const float4*)(p.wv[mat] + off);
        float4 v1 = *(const float4*)(p.wv[mat] + off + 4);
        unsigned short* d = (unsigned short*)p.wdst + (size_t)(4 + mat) * M1 + off;
        *(ushort4*)d       = cvt4(v0);
        *(ushort4*)(d + 4) = cvt4(v1);
    }
}

// ---------------- split-K reduces (bf16 partials, f32 accum) ----------------

__device__ __forceinline__ void reduce_slices(const unsigned short* src,
                                              unsigned short* dst,
                                              int h, int r, int nslice)
{
    float acc[8] = {0, 0, 0, 0, 0, 0, 0, 0};
    for (int s = 0; s < nslice; ++s) {
        u16x8 v = *(const u16x8*)(src + ((size_t)(h * nslice + s) << 20) + r);
        #pragma unroll
        for (int j = 0; j < 8; ++j)
            acc[j] += __uint_as_float(((unsigned)v[j]) << 16);
    }
    u16x8 o;
    #pragma unroll
    for (int j = 0; j < 8; ++j) {
        bf16 hh = __float2bfloat16(acc[j]);
        o[j] = *(unsigned short*)&hh;
    }
    *(u16x8*)(dst + ((size_t)h << 20) + r) = o;
}

__global__ void reduce_GM(const unsigned short* Gp, const unsigned short* Mp,
                          unsigned short* Gd, unsigned short* Md)
{
    const int b = blockIdx.x, t = threadIdx.x;
    if (b < 1024) {
        const int e = (b * 256 + t) * 8;
        reduce_slices(Gp, Gd, e >> 20, e & (M1 - 1), 8);
    } else {
        const int e = ((b - 1024) * 256 + t) * 8;
        reduce_slices(Mp, Md, e >> 20, e & (M1 - 1), 2);
    }
}

__global__ void reduce_4(const unsigned short* Sp, unsigned short* Dd)
{
    const int e = (blockIdx.x * 256 + threadIdx.x) * 8;
    reduce_slices(Sp, Dd, e >> 20, e & (M1 - 1), 4);
}

// ---------------- driver (R6 schedule, unchanged) ----------------

extern "C" void kernel_launch(void* const* d_in, const int* in_sizes, int n_in,
                              void* d_out, int out_size, void* d_ws, size_t ws_size,
                              hipStream_t stream)
{
    // ws layout (bf16 elems): peak 68 MB
    bf16* xb   = (bf16*)d_ws;                  // 8M elems
    bf16* xt   = xb + 8 * M1;                  // 8M
    bf16* wdst = xt + 8 * M1;                  // 6M
    bf16* Mp   = wdst + 6 * M1;                // 4M
    bf16* Mb   = Mp + 4 * M1;                  // 2M
    bf16* Gb   = Mb + 2 * M1;                  // 2M
    bf16* Ytb  = Gb + 2 * M1;                  // 2M
    bf16* Utb  = Ytb + 2 * M1;                 // 2M

    bf16* scr = (bf16*)d_out;                  // 32 MB scratch until final O

    PrepArgs pa;
    pa.x = (const float*)d_in[0];
    pa.w[0] = (const float*)d_in[1];  pa.w[1] = (const float*)d_in[2];
    pa.w[2] = (const float*)d_in[3];  pa.w[3] = (const float*)d_in[4];
    pa.wv[0] = (const float*)d_in[5]; pa.wv[1] = (const float*)d_in[6];
    pa.xb = xb; pa.xt = xt; pa.wdst = wdst;
    prep<<<4096, 256, 0, stream>>>(pa);

    GB g;

    // B1: z 0..15: G_h split-K8 (Ksub=512); z 16..19: M_h split-K2. 1280 blocks.
    for (int z = 0; z < 16; ++z) {
        const int h = z >> 3, s = z & 7;
        g.A[z] = xt + (size_t)h * 4 * M1 + s * 512;  g.lda[z] = 4096;
        g.B[z] = g.A[z];                             g.ldb[z] = 4096;
        g.C[z] = (bf16*)scr + (size_t)z * M1;
    }
    for (int z = 16; z < 20; ++z) {
        const int j = z - 16, h = j >> 1, s = j & 1;
        g.A[z] = wdst + (size_t)h * M1 + s * 512;           g.lda[z] = 1024;
        g.B[z] = wdst + (size_t)(2 + h) * M1 + s * 512;     g.ldb[z] = 1024;
        g.C[z] = Mp + (size_t)j * M1;
    }
    gemm_bt_pa<128, 128, bf16><<<dim3(8, 8, 20), 256, 0, stream>>>(g, 512, 1024);

    reduce_GM<<<2048, 256, 0, stream>>>((const unsigned short*)scr, (const unsigned short*)Mp,
                                        (unsigned short*)Gb, (unsigned short*)Mb);

    // L4: Yt = M G (split-K4, Ksub=256), 512 blocks
    for (int z = 0; z < 8; ++z) {
        const int h = z >> 2, s = z & 3;
        g.A[z] = Mb + (size_t)h * M1 + s * 256;  g.lda[z] = 1024;
        g.B[z] = Gb + (size_t)h * M1 + s * 256;  g.ldb[z] = 1024;
        g.C[z] = (bf16*)scr + (size_t)z * M1;
    }
    gemm_bt_pa<128, 128, bf16><<<dim3(8, 8, 8), 256, 0, stream>>>(g, 256, 1024);

    reduce_4<<<1024, 256, 0, stream>>>((const unsigned short*)scr, (unsigned short*)Ytb);

    // L6: Ut = gemm_bt(Wv, Yt) (split-K4), 512 blocks
    for (int z = 0; z < 8; ++z) {
        const int h = z >> 2, s = z & 3;
        g.A[z] = wdst + (size_t)(4 + h) * M1 + s * 256;  g.lda[z] = 1024;
        g.B[z] = Ytb + (size_t)h * M1 + s * 256;         g.ldb[z] = 1024;
        g.C[z] = (bf16*)scr + (size_t)z * M1;
    }
    gemm_bt_pa<128, 128, bf16><<<dim3(8, 8, 8), 256, 0, stream>>>(g, 256, 1024);

    reduce_4<<<1024, 256, 0, stream>>>((const unsigned short*)scr, (unsigned short*)Utb);

    // L8: O_h = gemm_bt(X_h, Ut_h) -> f32 out[:, h*1024:]  (128x64 tile, 1024 blocks)
    for (int z = 0; z < 2; ++z) {
        g.A[z] = xb + (size_t)z * 1024;   g.lda[z] = 2048;
        g.B[z] = Utb + (size_t)z * M1;    g.ldb[z] = 1024;
        g.C[z] = (float*)d_out + (size_t)z * 1024;
    }
    gemm_bt_pa<128, 64, float><<<dim3(16, 32, 2), 256, 0, stream>>>(g, 1024, 2048);
}

// Round 13
// 119.915 us; speedup vs baseline: 1.1605x; 1.0366x over previous
//
#include <hip/hip_runtime.h>
#include <hip/hip_bf16.h>

// Gram reassociation (no softmax in reference):
//   O_h = Q K^T V = X_h * U_h,  U_h = M G Wv^T,  M = Wq^T Wk,  G = X_h^T X_h
// DAG: prep -> B1{G-upper-tri splitK8 || M splitK2, merged grid} -> redGM
//   (reduce compact G partials + MIRROR to full G; reduce M) ->
//   Yt=M G (splitK4) -> red4 -> Ut=Wv Yt^T.. (splitK4) -> red4 -> O=X Ut^T.
// R13 = R12 with the M operand-order bug fixed: M = gemm_bt(WqT, WkT)
//   (R12 accidentally computed M^T by swapping A/B -> absmax 9472).
// G symmetric: only 36/64 upper-tri tiles computed; mirrored in redGM.
// K-loop: dbuf + counted vmcnt + full sched_barrier fencing (deterministic).

using bf16 = __hip_bfloat16;
typedef __attribute__((ext_vector_type(8))) __bf16 bf16x8;
typedef __attribute__((ext_vector_type(8))) unsigned short u16x8;
typedef __attribute__((ext_vector_type(4))) float f32x4;

#define M1 (1024 * 1024)

struct GB {   // per-z batch (blockIdx.z-indexed, wave-uniform)
    const bf16* A[8];
    const bf16* B[8];
    void*       C[8];
    int lda[8];
    int ldb[8];
};

__device__ __forceinline__ void gload_lds16(const void* g, void* l) {
    __builtin_amdgcn_global_load_lds(
        (const __attribute__((address_space(1))) void*)g,
        (__attribute__((address_space(3))) void*)l, 16, 0, 0);
}

template<int N>
__device__ __forceinline__ void waitv() {
    if constexpr (N == 4)      asm volatile("s_waitcnt vmcnt(4)" ::: "memory");
    else if constexpr (N == 3) asm volatile("s_waitcnt vmcnt(3)" ::: "memory");
    else                       asm volatile("s_waitcnt vmcnt(0)" ::: "memory");
}

// ---- shared GEMM core: C(+m0,n0 tile) = A B^T over Ksub, bt-form ----
template<int BM_, int BN_, typename OUT_T>
__device__ __forceinline__ void gemm_core(
    const bf16* __restrict__ A, int lda,
    const bf16* __restrict__ B, int ldb,
    OUT_T* __restrict__ C, int ldc,
    int m0, int n0, int Ksub,
    unsigned short* smem, int tid)
{
    auto As = (unsigned short(*)[BM_ * 32])smem;                   // [2][BM_*32]
    auto Bs = (unsigned short(*)[BN_ * 32])(smem + 2 * BM_ * 32);  // [2][BN_*32]

    constexpr int MI = BM_ / 32;
    constexpr int NI = BN_ / 32;
    constexpr int NLOADS = (BM_ + BN_) / 64;

    const int lane = tid & 63;
    const int wave = tid >> 6;
    const int wm   = wave >> 1;
    const int wn   = wave & 1;
    const int fr = lane & 15;
    const int kg = lane >> 4;
    const int srow = tid >> 2;
    const int scol = (tid & 3) * 8;

    auto stage = [&](int buf, int kt) {
        #pragma unroll
        for (int r = 0; r < BM_ / 64; ++r)
            gload_lds16(A + (size_t)(m0 + r * 64 + srow) * lda + (kt + scol),
                        &As[buf][(r * 64 + srow) * 32 + scol]);
        #pragma unroll
        for (int r = 0; r < BN_ / 64; ++r)
            gload_lds16(B + (size_t)(n0 + r * 64 + srow) * ldb + (kt + scol),
                        &Bs[buf][(r * 64 + srow) * 32 + scol]);
    };

    f32x4 acc[MI][NI];
    #pragma unroll
    for (int i = 0; i < MI; ++i)
        #pragma unroll
        for (int j = 0; j < NI; ++j)
            acc[i][j] = {0.f, 0.f, 0.f, 0.f};

    const int niter = Ksub >> 5;
    int cur = 0;
    stage(0, 0);

    for (int it = 0; it < niter; ++it) {
        if (it + 1 < niter) {
            stage(cur ^ 1, (it + 1) << 5);
            waitv<NLOADS>();
        } else {
            waitv<0>();
        }
        __builtin_amdgcn_s_barrier();
        __builtin_amdgcn_sched_barrier(0);

        bf16x8 afrag[MI], bfrag[NI];
        #pragma unroll
        for (int mi = 0; mi < MI; ++mi)
            afrag[mi] = *(const bf16x8*)&As[cur][(wm * (BM_ / 2) + mi * 16 + fr) * 32 + kg * 8];
        #pragma unroll
        for (int ni = 0; ni < NI; ++ni)
            bfrag[ni] = *(const bf16x8*)&Bs[cur][(wn * (BN_ / 2) + ni * 16 + fr) * 32 + kg * 8];

        #pragma unroll
        for (int mi = 0; mi < MI; ++mi)
            #pragma unroll
            for (int ni = 0; ni < NI; ++ni)
                acc[mi][ni] = __builtin_amdgcn_mfma_f32_16x16x32_bf16(
                    afrag[mi], bfrag[ni], acc[mi][ni], 0, 0, 0);

        __builtin_amdgcn_sched_barrier(0);
        __builtin_amdgcn_s_barrier();
        __builtin_amdgcn_sched_barrier(0);
        cur ^= 1;
    }

    // epilogue: acc -> LDS tile -> coalesced stores
    // C/D layout: col = lane&15, row = (lane>>4)*4 + j  [m89-verified]
    if constexpr (sizeof(OUT_T) == 2) {
        #pragma unroll
        for (int mi = 0; mi < MI; ++mi)
            #pragma unroll
            for (int ni = 0; ni < NI; ++ni) {
                const int c = wn * (BN_ / 2) + ni * 16 + fr;
                #pragma unroll
                for (int j = 0; j < 4; ++j) {
                    const int r = wm * (BM_ / 2) + mi * 16 + kg * 4 + j;
                    bf16 h = __float2bfloat16(acc[mi][ni][j]);
                    smem[r * BN_ + c] = *(unsigned short*)&h;
                }
            }
        __syncthreads();
        constexpr int V = (BM_ * BN_) / 2048;
        #pragma unroll
        for (int v = 0; v < V; ++v) {
            const int off = v * 2048 + tid * 8;
            const int r = off / BN_;
            const int c = off % BN_;
            *(u16x8*)((unsigned short*)C + (size_t)(m0 + r) * ldc + n0 + c) =
                *(const u16x8*)&smem[off];
        }
    } else {
        float* fs = (float*)smem;
        #pragma unroll
        for (int mi = 0; mi < MI; ++mi)
            #pragma unroll
            for (int ni = 0; ni < NI; ++ni) {
                const int c = wn * (BN_ / 2) + ni * 16 + fr;
                #pragma unroll
                for (int j = 0; j < 4; ++j) {
                    const int r = wm * (BM_ / 2) + mi * 16 + kg * 4 + j;
                    fs[r * BN_ + c] = acc[mi][ni][j];
                }
            }
        __syncthreads();
        constexpr int V = (BM_ * BN_) / 1024;
        #pragma unroll
        for (int v = 0; v < V; ++v) {
            const int off = v * 1024 + tid * 4;
            const int r = off / BN_;
            const int c = off % BN_;
            *(float4*)((float*)C + (size_t)(m0 + r) * ldc + n0 + c) =
                *(const float4*)&fs[off];
        }
    }
}

// ---- generic batched GEMM (L4, L6, O) ----
template<int BM_, int BN_, typename OUT_T>
__global__ __launch_bounds__(256, 4)
void gemm_bt_pa(GB g, int Ksub, int ldc)
{
    constexpr int STAGE_SH = 2 * (BM_ + BN_) * 32;
    constexpr int EPI_SH   = BM_ * BN_ * (int)sizeof(OUT_T) / 2;
    constexpr int SMEM_SH  = STAGE_SH > EPI_SH ? STAGE_SH : EPI_SH;
    __shared__ __align__(16) unsigned short smem[SMEM_SH];

    const int gx = gridDim.x, gy = gridDim.y;
    const int nwg = gx * gy * gridDim.z;
    const int orig = blockIdx.x + gx * (blockIdx.y + gy * blockIdx.z);
    const int cpx = nwg >> 3;
    const int wg = (orig & 7) * cpx + (orig >> 3);
    const int bx = wg % gx;
    const int by = (wg / gx) % gy;
    const int bz = wg / (gx * gy);

    gemm_core<BM_, BN_, OUT_T>(g.A[bz], g.lda[bz], g.B[bz], g.ldb[bz],
                               (OUT_T*)g.C[bz], ldc,
                               by * BM_, bx * BN_, Ksub,
                               smem, threadIdx.x);
}

// ---- B1: G upper-triangle (36 tiles compact, splitK8) || M (splitK2) ----
// grid (52, 1, 16), 832 blocks. bx<36: G tile; bx>=36: M.
struct B1Args {
    const bf16* xt;      // [2048][4096]
    const bf16* wdst;    // WqT0,WqT1,WkT0,WkT1,Wv0,Wv1
    bf16* Gp;            // compact partials [16 z][36 tiles][128*128]
    bf16* Mp;            // [4][1024*1024]
};

__global__ __launch_bounds__(256, 4)
void b1_kernel(B1Args a)
{
    __shared__ __align__(16) unsigned short smem[16384];   // 32 KB

    const int nwg = 832;
    const int orig = blockIdx.x + 52 * blockIdx.z;
    const int cpx = nwg >> 3;
    const int wg = (orig & 7) * cpx + (orig >> 3);
    const int bx = wg % 52;
    const int bz = wg / 52;

    if (bx < 36) {
        const int h = bz >> 3, s = bz & 7;
        int ti = 0, rem = bx;
        while (rem >= 8 - ti) { rem -= 8 - ti; ++ti; }
        const int tj = ti + rem;
        const bf16* A = a.xt + (size_t)(h * 1024 + ti * 128) * 4096 + s * 512;
        const bf16* B = a.xt + (size_t)(h * 1024 + tj * 128) * 4096 + s * 512;
        bf16* C = a.Gp + ((size_t)bz * 36 + bx) * 16384;
        gemm_core<128, 128, bf16>(A, 4096, B, 4096, C, 128, 0, 0, 512,
                                  smem, threadIdx.x);
    } else {
        const int combo = bz & 3;            // (h,s)
        const int h = combo >> 1, s = combo & 1;
        const int tile = (bz >> 2) * 16 + (bx - 36);   // 0..63
        const int m0 = (tile >> 3) * 128;
        const int n0 = (tile & 7) * 128;
        // M = gemm_bt(WqT, WkT) = Wq^T Wk   (R11-proven operand order!)
        const bf16* A = a.wdst + (size_t)h * M1 + s * 512;         // WqT_h
        const bf16* B = a.wdst + (size_t)(2 + h) * M1 + s * 512;   // WkT_h
        bf16* C = a.Mp + (size_t)combo * M1;
        gemm_core<128, 128, bf16>(A, 1024, B, 1024, C, 1024, m0, n0, 512,
                                  smem, threadIdx.x);
    }
}

// ---------------- prep: casts + transposes ----------------

__device__ __forceinline__ ushort4 cvt4(float4 v) {
    ushort4 o; bf16 h;
    h = __float2bfloat16(v.x); o.x = *(unsigned short*)&h;
    h = __float2bfloat16(v.y); o.y = *(unsigned short*)&h;
    h = __float2bfloat16(v.z); o.z = *(unsigned short*)&h;
    h = __float2bfloat16(v.w); o.w = *(unsigned short*)&h;
    return o;
}

struct PrepArgs {
    const float* x;
    const float* w[4];    // Wq1, Wq2, Wk1, Wk2 (to transpose)
    const float* wv[2];   // Wv1, Wv2 (straight)
    bf16* xb;
    bf16* xt;
    bf16* wdst;
};

__device__ void xpose64(const float* __restrict__ src, int ldsrc,
                        int r0, int c0,
                        bf16* __restrict__ dstS, int ldS,
                        bf16* __restrict__ dstT, int ldT,
                        float (*tile)[65], int t)
{
    const int tr  = t >> 4;
    const int tc4 = (t & 15) * 4;
    #pragma unroll
    for (int ph = 0; ph < 4; ++ph) {
        const int row = ph * 16 + tr;
        float4 v = *(const float4*)(src + (size_t)(r0 + row) * ldsrc + c0 + tc4);
        tile[row][tc4 + 0] = v.x;
        tile[row][tc4 + 1] = v.y;
        tile[row][tc4 + 2] = v.z;
        tile[row][tc4 + 3] = v.w;
        if (dstS)
            *(ushort4*)((unsigned short*)dstS + (size_t)(r0 + row) * ldS + c0 + tc4) = cvt4(v);
    }
    __syncthreads();
    #pragma unroll
    for (int ph = 0; ph < 4; ++ph) {
        const int crow = ph * 16 + tr;
        float4 v = {tile[tc4 + 0][crow], tile[tc4 + 1][crow],
                    tile[tc4 + 2][crow], tile[tc4 + 3][crow]};
        *(ushort4*)((unsigned short*)dstT + (size_t)(c0 + crow) * ldT + r0 + tc4) = cvt4(v);
    }
}

__global__ void prep(PrepArgs p)
{
    __shared__ float tile[64][65];
    const int b = blockIdx.x;
    const int t = threadIdx.x;

    if (b < 2048) {
        const int n0 = (b & 63) * 64;
        const int c0 = (b >> 6) * 64;
        xpose64(p.x, 2048, n0, c0, p.xb, 2048, p.xt, 4096, tile, t);
    } else if (b < 3072) {
        const int i = b - 2048;
        const int mat = i >> 8;
        const int tl  = i & 255;
        const int r0 = (tl & 15) * 64;
        const int c0 = (tl >> 4) * 64;
        xpose64(p.w[mat], 1024, r0, c0, nullptr, 0,
                p.wdst + (size_t)mat * M1, 1024, tile, t);
    } else {
        const int i = b - 3072;
        const int mat = i >> 9;
        const int blk = i & 511;
        const size_t off = (size_t)blk * 2048 + t * 8;
        float4 v0 = *(const float4*)(p.wv[mat] + off);
        float4 v1 = *(const float4*)(p.wv[mat] + off + 4);
        unsigned short* d = (unsigned short*)p.wdst + (size_t)(4 + mat) * M1 + off;
        *(ushort4*)d       = cvt4(v0);
        *(ushort4*)(d + 4) = cvt4(v1);
    }
}

// ---------------- reduces ----------------

__device__ __forceinline__ void reduce_slices(const unsigned short* src,
                                              unsigned short* dst,
                                              int h, int r, int nslice)
{
    float acc[8] = {0, 0, 0, 0, 0, 0, 0, 0};
    for (int s = 0; s < nslice; ++s) {
        u16x8 v = *(const u16x8*)(src + ((size_t)(h * nslice + s) << 20) + r);
        #pragma unroll
        for (int j = 0; j < 8; ++j)
            acc[j] += __uint_as_float(((unsigned)v[j]) << 16);
    }
    u16x8 o;
    #pragma unroll
    for (int j = 0; j < 8; ++j) {
        bf16 hh = __float2bfloat16(acc[j]);
        o[j] = *(unsigned short*)&hh;
    }
    *(u16x8*)(dst + ((size_t)h << 20) + r) = o;
}

// blocks 0..575: reduce compact G partials (8 slices) -> full mirrored G.
// blocks 576..1599: reduce M (2 slices).
__global__ void reduce_GM(const unsigned short* Gp, const unsigned short* Mp,
                          unsigned short* Gd, unsigned short* Md)
{
    const int b = blockIdx.x, t = threadIdx.x;
    if (b < 576) {
        const int h    = b / 288;
        const int rem  = b - h * 288;
        const int tile = rem >> 3;
        const int blk  = rem & 7;
        int ti = 0, trem = tile;
        while (trem >= 8 - ti) { trem -= 8 - ti; ++ti; }
        const int tj = ti + trem;

        const int e  = blk * 2048 + t * 8;
        const int r  = e >> 7;
        const int c0 = e & 127;

        float acc[8] = {0, 0, 0, 0, 0, 0, 0, 0};
        for (int s = 0; s < 8; ++s) {
            u16x8 v = *(const u16x8*)(Gp + ((size_t)(h * 8 + s) * 36 + tile) * 16384 + e);
            #pragma unroll
            for (int j = 0; j < 8; ++j)
                acc[j] += __uint_as_float(((unsigned)v[j]) << 16);
        }
        u16x8 o;
        #pragma unroll
        for (int j = 0; j < 8; ++j) {
            bf16 hh = __float2bfloat16(acc[j]);
            o[j] = *(unsigned short*)&hh;
        }
        unsigned short* G = Gd + (size_t)h * M1;
        *(u16x8*)(G + (size_t)(ti * 128 + r) * 1024 + tj * 128 + c0) = o;
        if (ti != tj) {
            #pragma unroll
            for (int j = 0; j < 8; ++j)
                G[(size_t)(tj * 128 + c0 + j) * 1024 + ti * 128 + r] = o[j];
        }
    } else {
        const int e = ((b - 576) * 256 + t) * 8;
        reduce_slices(Mp, Md, e >> 20, e & (M1 - 1), 2);
    }
}

__global__ void reduce_4(const unsigned short* Sp, unsigned short* Dd)
{
    const int e = (blockIdx.x * 256 + threadIdx.x) * 8;
    reduce_slices(Sp, Dd, e >> 20, e & (M1 - 1), 4);
}

// ---------------- driver ----------------

extern "C" void kernel_launch(void* const* d_in, const int* in_sizes, int n_in,
                              void* d_out, int out_size, void* d_ws, size_t ws_size,
                              hipStream_t stream)
{
    // ws layout (bf16 elems): peak 68 MB
    bf16* xb   = (bf16*)d_ws;                  // 8M elems
    bf16* xt   = xb + 8 * M1;                  // 8M
    bf16* wdst = xt + 8 * M1;                  // 6M
    bf16* Mp   = wdst + 6 * M1;                // 4M
    bf16* Mb   = Mp + 4 * M1;                  // 2M
    bf16* Gb   = Mb + 2 * M1;                  // 2M
    bf16* Ytb  = Gb + 2 * M1;                  // 2M
    bf16* Utb  = Ytb + 2 * M1;                 // 2M

    bf16* scr = (bf16*)d_out;                  // 32 MB scratch until final O

    PrepArgs pa;
    pa.x = (const float*)d_in[0];
    pa.w[0] = (const float*)d_in[1];  pa.w[1] = (const float*)d_in[2];
    pa.w[2] = (const float*)d_in[3];  pa.w[3] = (const float*)d_in[4];
    pa.wv[0] = (const float*)d_in[5]; pa.wv[1] = (const float*)d_in[6];
    pa.xb = xb; pa.xt = xt; pa.wdst = wdst;
    prep<<<4096, 256, 0, stream>>>(pa);

    // B1: G upper-tri (16 z x 36 tiles, compact partials in scr) || M
    B1Args b1;
    b1.xt = xt; b1.wdst = wdst; b1.Gp = scr; b1.Mp = Mp;
    b1_kernel<<<dim3(52, 1, 16), 256, 0, stream>>>(b1);

    // redGM: 576 G-blocks (reduce+mirror) + 1024 M-blocks
    reduce_GM<<<1600, 256, 0, stream>>>((const unsigned short*)scr,
                                        (const unsigned short*)Mp,
                                        (unsigned short*)Gb, (unsigned short*)Mb);

    GB g;

    // L4: Yt = M G (split-K4, Ksub=256), 512 blocks
    for (int z = 0; z < 8; ++z) {
        const int h = z >> 2, s = z & 3;
        g.A[z] = Mb + (size_t)h * M1 + s * 256;  g.lda[z] = 1024;
        g.B[z] = Gb + (size_t)h * M1 + s * 256;  g.ldb[z] = 1024;
        g.C[z] = (bf16*)scr + (size_t)z * M1;
    }
    gemm_bt_pa<128, 128, bf16><<<dim3(8, 8, 8), 256, 0, stream>>>(g, 256, 1024);

    reduce_4<<<1024, 256, 0, stream>>>((const unsigned short*)scr, (unsigned short*)Ytb);

    // L6: Ut = gemm_bt(Wv, Yt) (split-K4), 512 blocks
    for (int z = 0; z < 8; ++z) {
        const int h = z >> 2, s = z & 3;
        g.A[z] = wdst + (size_t)(4 + h) * M1 + s * 256;  g.lda[z] = 1024;
        g.B[z] = Ytb + (size_t)h * M1 + s * 256;         g.ldb[z] = 1024;
        g.C[z] = (bf16*)scr + (size_t)z * M1;
    }
    gemm_bt_pa<128, 128, bf16><<<dim3(8, 8, 8), 256, 0, stream>>>(g, 256, 1024);

    reduce_4<<<1024, 256, 0, stream>>>((const unsigned short*)scr, (unsigned short*)Utb);

    // O: O_h = gemm_bt(X_h, Ut_h) -> f32 out[:, h*1024:]  (128x64 tile, 1024 blocks)
    for (int z = 0; z < 2; ++z) {
        g.A[z] = xb + (size_t)z * 1024;   g.lda[z] = 2048;
        g.B[z] = Utb + (size_t)z * M1;    g.ldb[z] = 1024;
        g.C[z] = (float*)d_out + (size_t)z * 1024;
    }
    gemm_bt_pa<128, 64, float><<<dim3(16, 32, 2), 256, 0, stream>>>(g, 1024, 2048);
}

// Round 15
// 115.311 us; speedup vs baseline: 1.2068x; 1.0399x over previous
//
#include <hip/hip_runtime.h>
#include <hip/hip_bf16.h>

// Gram reassociation (no softmax in reference):
//   O_h = X_h * U_h,  U_h = M G Wv^T,  M = Wq^T Wk,  G = X_h^T X_h
// DAG: prep -> B1{G-upper-tri splitK8 || M full-K, merged} -> redG (mirror) ->
//   Yt=M G (splitK4) -> red4 -> Ut=gemm_bt(Wv,Yt) (splitK4) -> red4 -> O.
// R14 changes (attacks measured per-iteration latency, ~3000cy/iter):
//   * BK=64: half the serial K-iterations per block at same staged bytes.
//   * T2 XOR-swizzle (rule #21 form): linear gload_lds dest + pre-swizzled
//     GLOBAL source col (col ^ ((row&7)<<3)) + same XOR on LDS read col.
//     (BK=64 linear would be a 16-way bank conflict on ds_read_b128.)
//   * M computed full-K (f32 accum) inside B1 -> M-reduce eliminated.
// K-loop fences: R11's proven s_barrier + sched_barrier(0) discipline.

using bf16 = __hip_bfloat16;
typedef __attribute__((ext_vector_type(8))) __bf16 bf16x8;
typedef __attribute__((ext_vector_type(8))) unsigned short u16x8;
typedef __attribute__((ext_vector_type(4))) float f32x4;

#define M1 (1024 * 1024)

struct GB {   // per-z batch (blockIdx.z-indexed, wave-uniform)
    const bf16* A[8];
    const bf16* B[8];
    void*       C[8];
    int lda[8];
    int ldb[8];
};

__device__ __forceinline__ void gload_lds16(const void* g, void* l) {
    __builtin_amdgcn_global_load_lds(
        (const __attribute__((address_space(1))) void*)g,
        (__attribute__((address_space(3))) void*)l, 16, 0, 0);
}

__device__ __forceinline__ void waitv0() {
    asm volatile("s_waitcnt vmcnt(0)" ::: "memory");
}

// ---- shared GEMM core: C(+m0,n0 tile) = A B^T over Ksub, bt-form, BK=64 ----
template<int BM_, int BN_, typename OUT_T>
__device__ __forceinline__ void gemm_core(
    const bf16* __restrict__ A, int lda,
    const bf16* __restrict__ B, int ldb,
    OUT_T* __restrict__ C, int ldc,
    int m0, int n0, int Ksub,
    unsigned short* smem, int tid)
{
    constexpr int BK = 64;
    unsigned short* As = smem;             // BM_*64 shorts
    unsigned short* Bs = smem + BM_ * BK;  // BN_*64 shorts

    constexpr int MI = BM_ / 32;
    constexpr int NI = BN_ / 32;

    const int lane = tid & 63;
    const int wave = tid >> 6;
    const int wm   = wave >> 1;
    const int wn   = wave & 1;
    const int fr = lane & 15;
    const int kg = lane >> 4;

    const int srow  = tid >> 3;            // 0..31
    const int scol  = (tid & 7) * 8;       // 0..56 (16B granules)
    const int scolg = scol ^ ((srow & 7) << 3);   // pre-swizzled global col

    f32x4 acc[MI][NI];
    #pragma unroll
    for (int i = 0; i < MI; ++i)
        #pragma unroll
        for (int j = 0; j < NI; ++j)
            acc[i][j] = {0.f, 0.f, 0.f, 0.f};

    const int niter = Ksub >> 6;
    for (int it = 0; it < niter; ++it) {
        const int kt = it << 6;
        #pragma unroll
        for (int r = 0; r < BM_ / 32; ++r)
            gload_lds16(A + (size_t)(m0 + r * 32 + srow) * lda + (kt + scolg),
                        &As[(r * 32 + srow) * BK + scol]);
        #pragma unroll
        for (int r = 0; r < BN_ / 32; ++r)
            gload_lds16(B + (size_t)(n0 + r * 32 + srow) * ldb + (kt + scolg),
                        &Bs[(r * 32 + srow) * BK + scol]);
        waitv0();
        __builtin_amdgcn_s_barrier();             // buf filled, all waves
        __builtin_amdgcn_sched_barrier(0);

        #pragma unroll
        for (int kk = 0; kk < 2; ++kk) {
            bf16x8 af[MI], bfg[NI];
            #pragma unroll
            for (int mi = 0; mi < MI; ++mi) {
                const int row = wm * (BM_ / 2) + mi * 16 + fr;
                const int c = (kk * 32 + kg * 8) ^ ((row & 7) << 3);
                af[mi] = *(const bf16x8*)&As[row * BK + c];
            }
            #pragma unroll
            for (int ni = 0; ni < NI; ++ni) {
                const int row = wn * (BN_ / 2) + ni * 16 + fr;
                const int c = (kk * 32 + kg * 8) ^ ((row & 7) << 3);
                bfg[ni] = *(const bf16x8*)&Bs[row * BK + c];
            }
            #pragma unroll
            for (int mi = 0; mi < MI; ++mi)
                #pragma unroll
                for (int ni = 0; ni < NI; ++ni)
                    acc[mi][ni] = __builtin_amdgcn_mfma_f32_16x16x32_bf16(
                        af[mi], bfg[ni], acc[mi][ni], 0, 0, 0);
        }

        __builtin_amdgcn_sched_barrier(0);        // reads done before...
        __builtin_amdgcn_s_barrier();             // ...anyone re-stages
        __builtin_amdgcn_sched_barrier(0);
    }

    // epilogue: acc -> LDS tile -> coalesced stores
    // C/D layout: col = lane&15, row = (lane>>4)*4 + j  [m89-verified]
    if constexpr (sizeof(OUT_T) == 2) {
        #pragma unroll
        for (int mi = 0; mi < MI; ++mi)
            #pragma unroll
            for (int ni = 0; ni < NI; ++ni) {
                const int c = wn * (BN_ / 2) + ni * 16 + fr;
                #pragma unroll
                for (int j = 0; j < 4; ++j) {
                    const int r = wm * (BM_ / 2) + mi * 16 + kg * 4 + j;
                    bf16 h = __float2bfloat16(acc[mi][ni][j]);
                    smem[r * BN_ + c] = *(unsigned short*)&h;
                }
            }
        __syncthreads();
        constexpr int V = (BM_ * BN_) / 2048;
        #pragma unroll
        for (int v = 0; v < V; ++v) {
            const int off = v * 2048 + tid * 8;
            const int r = off / BN_;
            const int c = off % BN_;
            *(u16x8*)((unsigned short*)C + (size_t)(m0 + r) * ldc + n0 + c) =
                *(const u16x8*)&smem[off];
        }
    } else {
        float* fs = (float*)smem;
        #pragma unroll
        for (int mi = 0; mi < MI; ++mi)
            #pragma unroll
            for (int ni = 0; ni < NI; ++ni) {
                const int c = wn * (BN_ / 2) + ni * 16 + fr;
                #pragma unroll
                for (int j = 0; j < 4; ++j) {
                    const int r = wm * (BM_ / 2) + mi * 16 + kg * 4 + j;
                    fs[r * BN_ + c] = acc[mi][ni][j];
                }
            }
        __syncthreads();
        constexpr int V = (BM_ * BN_) / 1024;
        #pragma unroll
        for (int v = 0; v < V; ++v) {
            const int off = v * 1024 + tid * 4;
            const int r = off / BN_;
            const int c = off % BN_;
            *(float4*)((float*)C + (size_t)(m0 + r) * ldc + n0 + c) =
                *(const float4*)&fs[off];
        }
    }
}

// ---- generic batched GEMM (L4, L6, O) ----
template<int BM_, int BN_, typename OUT_T>
__global__ __launch_bounds__(256, 4)
void gemm_bt_pa(GB g, int Ksub, int ldc)
{
    constexpr int STAGE_SH = (BM_ + BN_) * 64;
    constexpr int EPI_SH   = BM_ * BN_ * (int)sizeof(OUT_T) / 2;
    constexpr int SMEM_SH  = STAGE_SH > EPI_SH ? STAGE_SH : EPI_SH;
    __shared__ __align__(16) unsigned short smem[SMEM_SH];

    const int gx = gridDim.x, gy = gridDim.y;
    const int nwg = gx * gy * gridDim.z;
    const int orig = blockIdx.x + gx * (blockIdx.y + gy * blockIdx.z);
    const int cpx = nwg >> 3;
    const int wg = (orig & 7) * cpx + (orig >> 3);
    const int bx = wg % gx;
    const int by = (wg / gx) % gy;
    const int bz = wg / (gx * gy);

    gemm_core<BM_, BN_, OUT_T>(g.A[bz], g.lda[bz], g.B[bz], g.ldb[bz],
                               (OUT_T*)g.C[bz], ldc,
                               by * BM_, bx * BN_, Ksub,
                               smem, threadIdx.x);
}

// ---- B1: G upper-tri (576 blk, splitK8, 8 iters) || M full-K (128 blk) ----
struct B1Args {
    const bf16* xt;      // [2048][4096]
    const bf16* wdst;    // WqT0,WqT1,WkT0,WkT1,Wv0,Wv1
    bf16* Gp;            // compact partials [16 z][36 tiles][128*128]
    bf16* Mb;            // [2][1024*1024] final M (no reduce)
};

__global__ __launch_bounds__(256, 4)
void b1_kernel(B1Args a)
{
    __shared__ __align__(16) unsigned short smem[16384];   // 32 KB

    const int nwg = 704;                     // 576 + 128
    const int orig = blockIdx.x;
    const int cpx = nwg >> 3;                // 88
    const int wg = (orig & 7) * cpx + (orig >> 3);

    if (wg < 576) {
        const int z = wg / 36;               // 0..15
        const int tile = wg - z * 36;
        const int h = z >> 3, s = z & 7;
        int ti = 0, rem = tile;
        while (rem >= 8 - ti) { rem -= 8 - ti; ++ti; }
        const int tj = ti + rem;
        const bf16* A = a.xt + (size_t)(h * 1024 + ti * 128) * 4096 + s * 512;
        const bf16* B = a.xt + (size_t)(h * 1024 + tj * 128) * 4096 + s * 512;
        bf16* C = a.Gp + ((size_t)z * 36 + tile) * 16384;
        gemm_core<128, 128, bf16>(A, 4096, B, 4096, C, 128, 0, 0, 512,
                                  smem, threadIdx.x);
    } else {
        const int idx = wg - 576;            // 0..127
        const int h = idx >> 6;
        const int tile = idx & 63;
        const int m0 = (tile >> 3) * 128;
        const int n0 = (tile & 7) * 128;
        // M = gemm_bt(WqT, WkT) = Wq^T Wk, full K=1024 (f32 accum, no reduce)
        const bf16* A = a.wdst + (size_t)h * M1;         // WqT_h
        const bf16* B = a.wdst + (size_t)(2 + h) * M1;   // WkT_h
        bf16* C = a.Mb + (size_t)h * M1;
        gemm_core<128, 128, bf16>(A, 1024, B, 1024, C, 1024, m0, n0, 1024,
                                  smem, threadIdx.x);
    }
}

// ---------------- prep: casts + transposes ----------------

__device__ __forceinline__ ushort4 cvt4(float4 v) {
    ushort4 o; bf16 h;
    h = __float2bfloat16(v.x); o.x = *(unsigned short*)&h;
    h = __float2bfloat16(v.y); o.y = *(unsigned short*)&h;
    h = __float2bfloat16(v.z); o.z = *(unsigned short*)&h;
    h = __float2bfloat16(v.w); o.w = *(unsigned short*)&h;
    return o;
}

struct PrepArgs {
    const float* x;
    const float* w[4];    // Wq1, Wq2, Wk1, Wk2 (to transpose)
    const float* wv[2];   // Wv1, Wv2 (straight)
    bf16* xb;
    bf16* xt;
    bf16* wdst;
};

__device__ void xpose64(const float* __restrict__ src, int ldsrc,
                        int r0, int c0,
                        bf16* __restrict__ dstS, int ldS,
                        bf16* __restrict__ dstT, int ldT,
                        float (*tile)[65], int t)
{
    const int tr  = t >> 4;
    const int tc4 = (t & 15) * 4;
    #pragma unroll
    for (int ph = 0; ph < 4; ++ph) {
        const int row = ph * 16 + tr;
        float4 v = *(const float4*)(src + (size_t)(r0 + row) * ldsrc + c0 + tc4);
        tile[row][tc4 + 0] = v.x;
        tile[row][tc4 + 1] = v.y;
        tile[row][tc4 + 2] = v.z;
        tile[row][tc4 + 3] = v.w;
        if (dstS)
            *(ushort4*)((unsigned short*)dstS + (size_t)(r0 + row) * ldS + c0 + tc4) = cvt4(v);
    }
    __syncthreads();
    #pragma unroll
    for (int ph = 0; ph < 4; ++ph) {
        const int crow = ph * 16 + tr;
        float4 v = {tile[tc4 + 0][crow], tile[tc4 + 1][crow],
                    tile[tc4 + 2][crow], tile[tc4 + 3][crow]};
        *(ushort4*)((unsigned short*)dstT + (size_t)(c0 + crow) * ldT + r0 + tc4) = cvt4(v);
    }
}

__global__ void prep(PrepArgs p)
{
    __shared__ float tile[64][65];
    const int b = blockIdx.x;
    const int t = threadIdx.x;

    if (b < 2048) {
        const int n0 = (b & 63) * 64;
        const int c0 = (b >> 6) * 64;
        xpose64(p.x, 2048, n0, c0, p.xb, 2048, p.xt, 4096, tile, t);
    } else if (b < 3072) {
        const int i = b - 2048;
        const int mat = i >> 8;
        const int tl  = i & 255;
        const int r0 = (tl & 15) * 64;
        const int c0 = (tl >> 4) * 64;
        xpose64(p.w[mat], 1024, r0, c0, nullptr, 0,
                p.wdst + (size_t)mat * M1, 1024, tile, t);
    } else {
        const int i = b - 3072;
        const int mat = i >> 9;
        const int blk = i & 511;
        const size_t off = (size_t)blk * 2048 + t * 8;
        float4 v0 = *(const float4*)(p.wv[mat] + off);
        float4 v1 = *(const float4*)(p.wv[mat] + off + 4);
        unsigned short* d = (unsigned short*)p.wdst + (size_t)(4 + mat) * M1 + off;
        *(ushort4*)d       = cvt4(v0);
        *(ushort4*)(d + 4) = cvt4(v1);
    }
}

// ---------------- reduces ----------------

__device__ __forceinline__ void reduce_slices(const unsigned short* src,
                                              unsigned short* dst,
                                              int h, int r, int nslice)
{
    float acc[8] = {0, 0, 0, 0, 0, 0, 0, 0};
    for (int s = 0; s < nslice; ++s) {
        u16x8 v = *(const u16x8*)(src + ((size_t)(h * nslice + s) << 20) + r);
        #pragma unroll
        for (int j = 0; j < 8; ++j)
            acc[j] += __uint_as_float(((unsigned)v[j]) << 16);
    }
    u16x8 o;
    #pragma unroll
    for (int j = 0; j < 8; ++j) {
        bf16 hh = __float2bfloat16(acc[j]);
        o[j] = *(unsigned short*)&hh;
    }
    *(u16x8*)(dst + ((size_t)h << 20) + r) = o;
}

// 576 blocks: reduce compact G partials (8 slices) -> full mirrored G.
__global__ void reduce_G(const unsigned short* Gp, unsigned short* Gd)
{
    const int b = blockIdx.x, t = threadIdx.x;
    const int h    = b / 288;
    const int rem  = b - h * 288;
    const int tile = rem >> 3;
    const int blk  = rem & 7;
    int ti = 0, trem = tile;
    while (trem >= 8 - ti) { trem -= 8 - ti; ++ti; }
    const int tj = ti + trem;

    const int e  = blk * 2048 + t * 8;
    const int r  = e >> 7;
    const int c0 = e & 127;

    float acc[8] = {0, 0, 0, 0, 0, 0, 0, 0};
    for (int s = 0; s < 8; ++s) {
        u16x8 v = *(const u16x8*)(Gp + ((size_t)(h * 8 + s) * 36 + tile) * 16384 + e);
        #pragma unroll
        for (int j = 0; j < 8; ++j)
            acc[j] += __uint_as_float(((unsigned)v[j]) << 16);
    }
    u16x8 o;
    #pragma unroll
    for (int j = 0; j < 8; ++j) {
        bf16 hh = __float2bfloat16(acc[j]);
        o[j] = *(unsigned short*)&hh;
    }
    unsigned short* G = Gd + (size_t)h * M1;
    *(u16x8*)(G + (size_t)(ti * 128 + r) * 1024 + tj * 128 + c0) = o;
    if (ti != tj) {
        #pragma unroll
        for (int j = 0; j < 8; ++j)
            G[(size_t)(tj * 128 + c0 + j) * 1024 + ti * 128 + r] = o[j];
    }
}

__global__ void reduce_4(const unsigned short* Sp, unsigned short* Dd)
{
    const int e = (blockIdx.x * 256 + threadIdx.x) * 8;
    reduce_slices(Sp, Dd, e >> 20, e & (M1 - 1), 4);
}

// ---------------- driver ----------------

extern "C" void kernel_launch(void* const* d_in, const int* in_sizes, int n_in,
                              void* d_out, int out_size, void* d_ws, size_t ws_size,
                              hipStream_t stream)
{
    // ws layout (bf16 elems): peak 64 MB
    bf16* xb   = (bf16*)d_ws;                  // 8M elems
    bf16* xt   = xb + 8 * M1;                  // 8M
    bf16* wdst = xt + 8 * M1;                  // 6M
    bf16* Mb   = wdst + 6 * M1;                // 2M
    bf16* Gb   = Mb + 2 * M1;                  // 2M
    bf16* Ytb  = Gb + 2 * M1;                  // 2M
    bf16* Utb  = Ytb + 2 * M1;                 // 2M

    bf16* scr = (bf16*)d_out;                  // 32 MB scratch until final O

    PrepArgs pa;
    pa.x = (const float*)d_in[0];
    pa.w[0] = (const float*)d_in[1];  pa.w[1] = (const float*)d_in[2];
    pa.w[2] = (const float*)d_in[3];  pa.w[3] = (const float*)d_in[4];
    pa.wv[0] = (const float*)d_in[5]; pa.wv[1] = (const float*)d_in[6];
    pa.xb = xb; pa.xt = xt; pa.wdst = wdst;
    prep<<<4096, 256, 0, stream>>>(pa);

    // B1: G upper-tri (compact partials in scr) || M full-K (direct to Mb)
    B1Args b1;
    b1.xt = xt; b1.wdst = wdst; b1.Gp = scr; b1.Mb = Mb;
    b1_kernel<<<704, 256, 0, stream>>>(b1);

    // redG: 576 blocks, reduce + mirror
    reduce_G<<<576, 256, 0, stream>>>((const unsigned short*)scr,
                                      (unsigned short*)Gb);

    GB g;

    // L4: Yt = M G (split-K4, Ksub=256 -> 4 iters), 512 blocks
    for (int z = 0; z < 8; ++z) {
        const int h = z >> 2, s = z & 3;
        g.A[z] = Mb + (size_t)h * M1 + s * 256;  g.lda[z] = 1024;
        g.B[z] = Gb + (size_t)h * M1 + s * 256;  g.ldb[z] = 1024;
        g.C[z] = (bf16*)scr + (size_t)z * M1;
    }
    gemm_bt_pa<128, 128, bf16><<<dim3(8, 8, 8), 256, 0, stream>>>(g, 256, 1024);

    reduce_4<<<1024, 256, 0, stream>>>((const unsigned short*)scr, (unsigned short*)Ytb);

    // L6: Ut = gemm_bt(Wv, Yt) (split-K4), 512 blocks
    for (int z = 0; z < 8; ++z) {
        const int h = z >> 2, s = z & 3;
        g.A[z] = wdst + (size_t)(4 + h) * M1 + s * 256;  g.lda[z] = 1024;
        g.B[z] = Ytb + (size_t)h * M1 + s * 256;         g.ldb[z] = 1024;
        g.C[z] = (bf16*)scr + (size_t)z * M1;
    }
    gemm_bt_pa<128, 128, bf16><<<dim3(8, 8, 8), 256, 0, stream>>>(g, 256, 1024);

    reduce_4<<<1024, 256, 0, stream>>>((const unsigned short*)scr, (unsigned short*)Utb);

    // O: O_h = gemm_bt(X_h, Ut_h) -> f32 out[:, h*1024:]  (128x64, 16 iters)
    for (int z = 0; z < 2; ++z) {
        g.A[z] = xb + (size_t)z * 1024;   g.lda[z] = 2048;
        g.B[z] = Utb + (size_t)z * M1;    g.ldb[z] = 1024;
        g.C[z] = (float*)d_out + (size_t)z * 1024;
    }
    gemm_bt_pa<128, 64, float><<<dim3(16, 32, 2), 256, 0, stream>>>(g, 1024, 2048);
}